// Round 6
// baseline (309.431 us; speedup 1.0000x reference)
//
#include <hip/hip_runtime.h>
#include <stdint.h>

#define S_     264
#define BL_    256
#define TWO_S  528
#define TWO_BL 512
#define B_     512
#define V_     128
#define NQ     392   // S + V
#define Z_     1024
#define N2_    1056  // S*4
#define NTOT   1184  // N2 + V

// ---------------------------------------------------------------------------
// Kernel 1: one block per (batch, psi). Register-staged single pass, unroll-4
// with 4 named register sets -> depth-3 software pipeline. Compiler inserts
// the exact vmcnt waits (no inline asm, no LDS staging for Psi).
// Wave w handles pairs (w + 4j), j=0..63; pair = rows (m, m+256).
// Fused accumulator u = coefY*t_y + coefS*t_sql.
// Also copies x_mag into out0 (first half) from psi==0 blocks.
// ---------------------------------------------------------------------------
__global__ __launch_bounds__(256) void k_psi(
    const float* __restrict__ x_mag, const float* __restrict__ x_phase,
    const float* __restrict__ y_e, const float* __restrict__ y_o,
    const float* __restrict__ Psi_e, const float* __restrict__ Psi_o,
    const float* __restrict__ d1, const float* __restrict__ d2,
    const float* __restrict__ d4,
    float* __restrict__ contrib, float* __restrict__ out0)
{
    const int tid = threadIdx.x;
    const int b   = blockIdx.x >> 1;
    const int psi = blockIdx.x & 1;
    const float* Psi = psi ? Psi_o : Psi_e;
    const float* yv  = psi ? y_o  : y_e;
    const float coefY = psi ? -d2[0] : -d1[0];
    const float coefS = psi ?  d4[0] :  d2[0];

    __shared__ float4 xs4[132];          // x = [mag*c, mag*s]
    __shared__ float  cs[S_], sn[S_];
    __shared__ float  gys[BL_];          // coefY * y
    __shared__ float4 redU4[4][132];

    float* xs = (float*)xs4;

    for (int s = tid; s < S_; s += 256) {
        float mag = x_mag[(size_t)b * S_ + s];
        float ph  = x_phase[(size_t)b * S_ + s];
        float c = cosf(ph), si = sinf(ph);
        cs[s] = c; sn[s] = si;
        xs[s]      = mag * c;
        xs[S_ + s] = mag * si;
        if (psi == 0) out0[(size_t)b * S_ + s] = mag;
    }
    gys[tid] = coefY * yv[(size_t)b * BL_ + tid];
    __syncthreads();

    const int wave = tid >> 6, lane = tid & 63;
    const float4 f4z = {0.f, 0.f, 0.f, 0.f};

    float4 x0 = xs4[lane];
    float4 x1 = xs4[lane + 64];
    float4 x2 = (lane < 4) ? xs4[lane + 128] : f4z;

    float4 u0 = f4z, u1 = f4z, u2 = f4z;

    const float4* Pg = (const float4*)(Psi + (size_t)b * TWO_BL * TWO_S);

#define LOADP(P, L0, L1, L2, H0, H1, H2) {                            \
        const float4* rl_ = Pg + (size_t)(P) * 132;                   \
        const float4* rh_ = rl_ + (size_t)BL_ * 132;                  \
        L0 = rl_[lane]; L1 = rl_[lane + 64];                          \
        H0 = rh_[lane]; H1 = rh_[lane + 64];                          \
        if (lane < 4) { L2 = rl_[lane + 128]; H2 = rh_[lane + 128]; } \
        else          { L2 = f4z; H2 = f4z; }                         \
    }

#define COMPUTE(L0, L1, L2, H0, H1, H2, PIDX) {                       \
        float a  = L0.x*x0.x + L0.y*x0.y + L0.z*x0.z + L0.w*x0.w      \
                 + L1.x*x1.x + L1.y*x1.y + L1.z*x1.z + L1.w*x1.w      \
                 + L2.x*x2.x + L2.y*x2.y + L2.z*x2.z + L2.w*x2.w;     \
        float bb = H0.x*x0.x + H0.y*x0.y + H0.z*x0.z + H0.w*x0.w      \
                 + H1.x*x1.x + H1.y*x1.y + H1.z*x1.z + H1.w*x1.w      \
                 + H2.x*x2.x + H2.y*x2.y + H2.z*x2.z + H2.w*x2.w;     \
        _Pragma("unroll")                                             \
        for (int off_ = 32; off_; off_ >>= 1) {                       \
            a  += __shfl_xor(a, off_);                                \
            bb += __shfl_xor(bb, off_);                               \
        }                                                             \
        float g  = gys[PIDX] + coefS * (a * a + bb * bb);             \
        float wl = a * g, wh = bb * g;                                \
        u0.x += L0.x*wl + H0.x*wh;  u0.y += L0.y*wl + H0.y*wh;        \
        u0.z += L0.z*wl + H0.z*wh;  u0.w += L0.w*wl + H0.w*wh;        \
        u1.x += L1.x*wl + H1.x*wh;  u1.y += L1.y*wl + H1.y*wh;        \
        u1.z += L1.z*wl + H1.z*wh;  u1.w += L1.w*wl + H1.w*wh;        \
        u2.x += L2.x*wl + H2.x*wh;  u2.y += L2.y*wl + H2.y*wh;        \
        u2.z += L2.z*wl + H2.z*wh;  u2.w += L2.w*wl + H2.w*wh;        \
    }

    // 4 named register sets; set X in block i holds pair (wave + 16i + 4X).
    float4 Al0, Al1, Al2, Ah0, Ah1, Ah2;
    float4 Bl0, Bl1, Bl2, Bh0, Bh1, Bh2;
    float4 Cl0, Cl1, Cl2, Ch0, Ch1, Ch2;
    float4 Dl0, Dl1, Dl2, Dh0, Dh1, Dh2;

    LOADP(wave,      Al0, Al1, Al2, Ah0, Ah1, Ah2);
    LOADP(wave + 4,  Bl0, Bl1, Bl2, Bh0, Bh1, Bh2);
    LOADP(wave + 8,  Cl0, Cl1, Cl2, Ch0, Ch1, Ch2);
    LOADP(wave + 12, Dl0, Dl1, Dl2, Dh0, Dh1, Dh2);

    for (int i = 0; i < 15; ++i) {
        const int base = wave + 16 * i;
        COMPUTE(Al0, Al1, Al2, Ah0, Ah1, Ah2, base);
        LOADP(base + 16, Al0, Al1, Al2, Ah0, Ah1, Ah2);
        COMPUTE(Bl0, Bl1, Bl2, Bh0, Bh1, Bh2, base + 4);
        LOADP(base + 20, Bl0, Bl1, Bl2, Bh0, Bh1, Bh2);
        COMPUTE(Cl0, Cl1, Cl2, Ch0, Ch1, Ch2, base + 8);
        LOADP(base + 24, Cl0, Cl1, Cl2, Ch0, Ch1, Ch2);
        COMPUTE(Dl0, Dl1, Dl2, Dh0, Dh1, Dh2, base + 12);
        LOADP(base + 28, Dl0, Dl1, Dl2, Dh0, Dh1, Dh2);
    }
    {   // epilogue block i = 15, no further loads
        const int base = wave + 16 * 15;
        COMPUTE(Al0, Al1, Al2, Ah0, Ah1, Ah2, base);
        COMPUTE(Bl0, Bl1, Bl2, Bh0, Bh1, Bh2, base + 4);
        COMPUTE(Cl0, Cl1, Cl2, Ch0, Ch1, Ch2, base + 8);
        COMPUTE(Dl0, Dl1, Dl2, Dh0, Dh1, Dh2, base + 12);
    }
#undef LOADP
#undef COMPUTE

    // per-wave partials -> LDS, cross-wave reduce
    redU4[wave][lane]      = u0;
    redU4[wave][lane + 64] = u1;
    if (lane < 4) redU4[wave][lane + 128] = u2;
    __syncthreads();

    const float* redU = (const float*)redU4;
    float* outp = contrib + (size_t)(b * 2 + psi) * S_;
    for (int s = tid; s < S_; s += 256) {
        float ul = 0.f, uh = 0.f;
        #pragma unroll
        for (int w = 0; w < 4; ++w) {
            ul += redU[w * TWO_S + s];
            uh += redU[w * TWO_S + S_ + s];
        }
        outp[s] = cs[s] * ul + sn[s] * uh;
    }
}

// ---------------------------------------------------------------------------
// GEMM1 (fused cat): z = relu([q, v] @ W1^T + b1), q = x_mag + contrib_e+o.
// Tile 32x64, thread 2x4, K-chunk 32.  (unchanged from round 4 — passed)
// ---------------------------------------------------------------------------
__global__ __launch_bounds__(256) void k_gemm1(
    const float* __restrict__ x_mag, const float* __restrict__ contrib,
    const float* __restrict__ v, const float* __restrict__ W1,
    const float* __restrict__ b1, float* __restrict__ z)
{
    const int tid = threadIdx.x;
    const int m0  = blockIdx.x * 32;
    const int n0  = blockIdx.y * 64;
    const int trow = (tid >> 4) * 2;        // 0..30
    const int tcol = (tid & 15) * 4;        // 0..60

    __shared__ float As[32][36];   // As[k][r]
    __shared__ float Ws[32][68];   // Ws[k][c]

    float acc[2][4] = {};

    const int krA  = tid >> 3;        // 0..31
    const int kkA  = (tid & 7) * 4;   // 0..28

    for (int kc = 0; kc < NQ; kc += 32) {
        {
            const int arow = m0 + krA;
            const int gk = kc + kkA;
            float4 vv = {0.f, 0.f, 0.f, 0.f};
            if (gk < S_) {
                float4 xm = *(const float4*)&x_mag[(size_t)arow * S_ + gk];
                float4 ce = *(const float4*)&contrib[(size_t)(arow * 2) * S_ + gk];
                float4 co = *(const float4*)&contrib[(size_t)(arow * 2 + 1) * S_ + gk];
                vv.x = xm.x + ce.x + co.x; vv.y = xm.y + ce.y + co.y;
                vv.z = xm.z + ce.z + co.z; vv.w = xm.w + ce.w + co.w;
            } else if (gk < NQ) {
                vv = *(const float4*)&v[(size_t)arow * V_ + (gk - S_)];
            }
            As[kkA + 0][krA] = vv.x; As[kkA + 1][krA] = vv.y;
            As[kkA + 2][krA] = vv.z; As[kkA + 3][krA] = vv.w;
        }
        for (int i = tid; i < 512; i += 256) {
            const int r  = i >> 3;
            const int j4 = (i & 7) * 4;
            const int gk = kc + j4;
            float4 vv = {0.f, 0.f, 0.f, 0.f};
            if (gk < NQ)
                vv = *(const float4*)&W1[(size_t)(n0 + r) * NQ + gk];
            Ws[j4 + 0][r] = vv.x; Ws[j4 + 1][r] = vv.y;
            Ws[j4 + 2][r] = vv.z; Ws[j4 + 3][r] = vv.w;
        }
        __syncthreads();

        #pragma unroll
        for (int k = 0; k < 32; ++k) {
            float2 a2 = *(const float2*)&As[k][trow];
            float4 w4 = *(const float4*)&Ws[k][tcol];
            acc[0][0] += a2.x * w4.x; acc[0][1] += a2.x * w4.y;
            acc[0][2] += a2.x * w4.z; acc[0][3] += a2.x * w4.w;
            acc[1][0] += a2.y * w4.x; acc[1][1] += a2.y * w4.y;
            acc[1][2] += a2.y * w4.z; acc[1][3] += a2.y * w4.w;
        }
        __syncthreads();
    }

    #pragma unroll
    for (int i = 0; i < 2; ++i) {
        const int row = m0 + trow + i;
        const int col = n0 + tcol;
        float4 r;
        r.x = fmaxf(acc[i][0] + b1[col + 0], 0.f);
        r.y = fmaxf(acc[i][1] + b1[col + 1], 0.f);
        r.z = fmaxf(acc[i][2] + b1[col + 2], 0.f);
        r.w = fmaxf(acc[i][3] + b1[col + 3], 0.f);
        *(float4*)&z[(size_t)row * Z_ + col] = r;
    }
}

// ---------------------------------------------------------------------------
// GEMM23 (fused): [out_oh | out_v] = z @ [W2;W3]^T + [b2;b3] + [oh | v]
// plus fused softmax-MAPP epilogue writing out0's second half.
// (unchanged from round 4 — passed)
// ---------------------------------------------------------------------------
__global__ __launch_bounds__(256) void k_gemm23(
    const float* __restrict__ z,
    const float* __restrict__ W2, const float* __restrict__ b2,
    const float* __restrict__ oh,
    const float* __restrict__ W3, const float* __restrict__ b3,
    const float* __restrict__ v,
    float* __restrict__ out_oh, float* __restrict__ out_v,
    float* __restrict__ out0)
{
    const int tid = threadIdx.x;
    const int m0  = blockIdx.x * 32;
    const int n0  = blockIdx.y * 64;
    const int trow = (tid >> 4) * 2;
    const int tcol = (tid & 15) * 4;

    __shared__ float As[32][36];
    __shared__ float Ws[32][68];

    float acc[2][4] = {};

    const int krA = tid >> 3;
    const int kkA = (tid & 7) * 4;

    for (int kc = 0; kc < Z_; kc += 32) {
        {
            float4 vv = *(const float4*)&z[(size_t)(m0 + krA) * Z_ + kc + kkA];
            As[kkA + 0][krA] = vv.x; As[kkA + 1][krA] = vv.y;
            As[kkA + 2][krA] = vv.z; As[kkA + 3][krA] = vv.w;
        }
        for (int i = tid; i < 512; i += 256) {
            const int r  = i >> 3;
            const int j4 = (i & 7) * 4;
            const int wrow = n0 + r;
            float4 vv = {0.f, 0.f, 0.f, 0.f};
            if (wrow < NTOT) {
                const float* wp = (wrow < N2_)
                    ? (W2 + (size_t)wrow * Z_)
                    : (W3 + (size_t)(wrow - N2_) * Z_);
                vv = *(const float4*)&wp[kc + j4];
            }
            Ws[j4 + 0][r] = vv.x; Ws[j4 + 1][r] = vv.y;
            Ws[j4 + 2][r] = vv.z; Ws[j4 + 3][r] = vv.w;
        }
        __syncthreads();

        #pragma unroll
        for (int k = 0; k < 32; ++k) {
            float2 a2 = *(const float2*)&As[k][trow];
            float4 w4 = *(const float4*)&Ws[k][tcol];
            acc[0][0] += a2.x * w4.x; acc[0][1] += a2.x * w4.y;
            acc[0][2] += a2.x * w4.z; acc[0][3] += a2.x * w4.w;
            acc[1][0] += a2.y * w4.x; acc[1][1] += a2.y * w4.y;
            acc[1][2] += a2.y * w4.z; acc[1][3] += a2.y * w4.w;
        }
        __syncthreads();
    }

    #pragma unroll
    for (int i = 0; i < 2; ++i) {
        const int row = m0 + trow + i;
        const int col = n0 + tcol;
        if (col < N2_) {
            float4 ad = *(const float4*)&oh[(size_t)row * N2_ + col];
            float4 r;
            r.x = acc[i][0] + b2[col + 0] + ad.x;
            r.y = acc[i][1] + b2[col + 1] + ad.y;
            r.z = acc[i][2] + b2[col + 2] + ad.z;
            r.w = acc[i][3] + b2[col + 3] + ad.w;
            *(float4*)&out_oh[(size_t)row * N2_ + col] = r;
            float m  = fmaxf(fmaxf(r.x, r.y), fmaxf(r.z, r.w));
            float e0 = expf(r.x - m), e1 = expf(r.y - m);
            float e2 = expf(r.z - m), e3 = expf(r.w - m);
            float sum = e0 + e1 + e2 + e3;
            float sym = (0.5f * e0 + 1.0f * e1 + 1.5f * e2 + 2.0f * e3) / sum;
            out0[(size_t)B_ * S_ + (size_t)row * S_ + (col >> 2)] = sym;
        } else if (col < NTOT) {
            const int c3 = col - N2_;
            float4 ad = *(const float4*)&v[(size_t)row * V_ + c3];
            float4 r;
            r.x = acc[i][0] + b3[c3 + 0] + ad.x;
            r.y = acc[i][1] + b3[c3 + 1] + ad.y;
            r.z = acc[i][2] + b3[c3 + 2] + ad.z;
            r.w = acc[i][3] + b3[c3 + 3] + ad.w;
            *(float4*)&out_v[(size_t)row * V_ + c3] = r;
        }
    }
}

// ---------------------------------------------------------------------------
extern "C" void kernel_launch(void* const* d_in, const int* in_sizes, int n_in,
                              void* d_out, int out_size, void* d_ws, size_t ws_size,
                              hipStream_t stream)
{
    const float* x_mag    = (const float*)d_in[1];
    const float* x_mag_oh = (const float*)d_in[2];
    const float* v        = (const float*)d_in[3];
    const float* x_phase  = (const float*)d_in[4];
    const float* y_e      = (const float*)d_in[5];
    const float* y_o      = (const float*)d_in[6];
    const float* Psi_e    = (const float*)d_in[7];
    const float* Psi_o    = (const float*)d_in[8];
    const float* W1       = (const float*)d_in[9];
    const float* b1       = (const float*)d_in[10];
    const float* W2       = (const float*)d_in[11];
    const float* b2       = (const float*)d_in[12];
    const float* W3       = (const float*)d_in[13];
    const float* b3       = (const float*)d_in[14];
    const float* d1       = (const float*)d_in[15];
    const float* d2       = (const float*)d_in[16];
    const float* d4       = (const float*)d_in[18];   // d3 (d_in[17]) unused

    float* ws      = (float*)d_ws;
    float* contrib = ws;                         // 1024 * 264
    float* z       = contrib + 1024 * S_;        // 512 * 1024

    float* out0   = (float*)d_out;               // 2*512*264 (x_mag_new)
    float* out_oh = out0 + 2 * B_ * S_;          // 512*1056  (x_mag_oh_new)
    float* out_v  = out_oh + B_ * N2_;           // 512*128   (v_new)

    k_psi<<<dim3(B_ * 2), dim3(256), 0, stream>>>(
        x_mag, x_phase, y_e, y_o, Psi_e, Psi_o, d1, d2, d4, contrib, out0);

    k_gemm1<<<dim3(16, 16), dim3(256), 0, stream>>>(
        x_mag, contrib, v, W1, b1, z);

    k_gemm23<<<dim3(16, 19), dim3(256), 0, stream>>>(
        z, W2, b2, x_mag_oh, W3, b3, v, out_oh, out_v, out0);
}

// Round 7
// 303.956 us; speedup vs baseline: 1.0180x; 1.0180x over previous
//
#include <hip/hip_runtime.h>
#include <stdint.h>

#define S_     264
#define BL_    256
#define TWO_S  528
#define TWO_BL 512
#define B_     512
#define V_     128
#define NQ     392   // S + V
#define Z_     1024
#define N2_    1056  // S*4
#define NTOT   1184  // N2 + V

#define CH_F4  528   // per chunk: 2 pairs x (lo row 132 + hi row 132) float4

// async global->LDS, 16 bytes per lane (LDS dest = wave-uniform base + lane*16)
__device__ __forceinline__ void gload_lds16(const void* g, void* l) {
    __builtin_amdgcn_global_load_lds(
        (const __attribute__((address_space(1))) uint32_t*)g,
        (__attribute__((address_space(3))) uint32_t*)l, 16, 0, 0);
}

// stage chunk c: pairs (half*128 + c*2 + {0,1}), 528 float4, linear dest.
__device__ __forceinline__ void stage2(const float4* Pg, int half, int c,
                                       float4* buf, int tid) {
    #pragma unroll
    for (int r = 0; r < 4; ++r) {
        const int i  = r * 128 + tid;          // 0..511
        const int pi = (i >= 264) ? 1 : 0;
        const int o  = i - pi * 264;
        const int m  = half * 128 + c * 2 + pi;
        const float4* src = Pg + (size_t)((o < 132) ? (m * 132 + o)
                                                    : ((m + BL_) * 132 + (o - 132)));
        gload_lds16((const void*)src, (void*)(buf + i));
    }
    if (tid < 16) {
        const int i = 512 + tid;               // pi=1, o=248..263 -> hi row
        const int m = half * 128 + c * 2 + 1;
        const float4* src = Pg + (size_t)((m + BL_) * 132 + (i - 264 - 132));
        gload_lds16((const void*)src, (void*)(buf + i));
    }
}

// ---------------------------------------------------------------------------
// Kernel 1: 2048 blocks x 128 threads; block = (batch, psi, half).
// Half a Psi[b] (128 row-pairs) per block, chunk = 2 pairs (one per wave),
// LDS double-buffered via gload_lds + barrier (r4's proven sync), but at
// EXACTLY 8 blocks/CU (LDS ~19.5KB) -> uniform residency, 8-way stagger.
// Fused accumulator u = coefY*t_y + coefS*t_sql. Partial output per half.
// Also copies x_mag into out0 from (psi==0, half==0) blocks.
// ---------------------------------------------------------------------------
__global__ __launch_bounds__(128) void k_psi(
    const float* __restrict__ x_mag, const float* __restrict__ x_phase,
    const float* __restrict__ y_e, const float* __restrict__ y_o,
    const float* __restrict__ Psi_e, const float* __restrict__ Psi_o,
    const float* __restrict__ d1, const float* __restrict__ d2,
    const float* __restrict__ d4,
    float* __restrict__ contribP, float* __restrict__ out0)
{
    const int tid  = threadIdx.x;
    const int b    = blockIdx.x >> 2;
    const int psi  = (blockIdx.x >> 1) & 1;
    const int half = blockIdx.x & 1;
    const float* Psi = psi ? Psi_o : Psi_e;
    const float* yv  = psi ? y_o  : y_e;
    const float coefY = psi ? -d2[0] : -d1[0];
    const float coefS = psi ?  d4[0] :  d2[0];

    __shared__ float4 bufA[CH_F4];       // 8448 B
    __shared__ float4 bufB[CH_F4];       // 8448 B
    __shared__ float4 xs4[132];          // x = [mag*c, mag*s], 2112 B
    __shared__ float  gys[128];          // coefY * y for this half, 512 B

    float* xs = (float*)xs4;

    for (int s = tid; s < S_; s += 128) {
        float mag = x_mag[(size_t)b * S_ + s];
        float ph  = x_phase[(size_t)b * S_ + s];
        xs[s]      = mag * cosf(ph);
        xs[S_ + s] = mag * sinf(ph);
        if (psi == 0 && half == 0) out0[(size_t)b * S_ + s] = mag;
    }
    gys[tid] = coefY * yv[(size_t)b * BL_ + half * 128 + tid];

    const float4* Pg = (const float4*)(Psi + (size_t)b * TWO_BL * TWO_S);

    stage2(Pg, half, 0, bufA, tid);
    __syncthreads();                     // drains stage0 + prologue LDS writes

    const int wave = tid >> 6, lane = tid & 63;
    const float4 f4z = {0.f, 0.f, 0.f, 0.f};

    float4 x0 = xs4[lane];
    float4 x1 = xs4[lane + 64];
    float4 x2 = (lane < 4) ? xs4[lane + 128] : f4z;

    float4 u0 = f4z, u1 = f4z, u2 = f4z;

    for (int c = 0; c < 64; ++c) {
        float4* cur = (c & 1) ? bufB : bufA;
        float4* nxt = (c & 1) ? bufA : bufB;
        if (c + 1 < 64) stage2(Pg, half, c + 1, nxt, tid);

        // wave w computes pair (c*2 + w): region cur + w*264
        const float4* bl = cur + wave * 264;
        const float4* bh = bl + 132;
        float4 l0 = bl[lane], l1 = bl[lane + 64];
        float4 h0 = bh[lane], h1 = bh[lane + 64];
        float4 l2 = f4z, h2 = f4z;
        if (lane < 4) { l2 = bl[lane + 128]; h2 = bh[lane + 128]; }

        float a  = l0.x*x0.x + l0.y*x0.y + l0.z*x0.z + l0.w*x0.w
                 + l1.x*x1.x + l1.y*x1.y + l1.z*x1.z + l1.w*x1.w
                 + l2.x*x2.x + l2.y*x2.y + l2.z*x2.z + l2.w*x2.w;
        float bb = h0.x*x0.x + h0.y*x0.y + h0.z*x0.z + h0.w*x0.w
                 + h1.x*x1.x + h1.y*x1.y + h1.z*x1.z + h1.w*x1.w
                 + h2.x*x2.x + h2.y*x2.y + h2.z*x2.z + h2.w*x2.w;
        #pragma unroll
        for (int off = 32; off; off >>= 1) {
            a  += __shfl_xor(a, off);
            bb += __shfl_xor(bb, off);
        }

        const float g  = gys[c * 2 + wave] + coefS * (a * a + bb * bb);
        const float wl = a * g, wh = bb * g;

        u0.x += l0.x*wl + h0.x*wh;  u0.y += l0.y*wl + h0.y*wh;
        u0.z += l0.z*wl + h0.z*wh;  u0.w += l0.w*wl + h0.w*wh;
        u1.x += l1.x*wl + h1.x*wh;  u1.y += l1.y*wl + h1.y*wh;
        u1.z += l1.z*wl + h1.z*wh;  u1.w += l1.w*wl + h1.w*wh;
        u2.x += l2.x*wl + h2.x*wh;  u2.y += l2.y*wl + h2.y*wh;
        u2.z += l2.z*wl + h2.z*wh;  u2.w += l2.w*wl + h2.w*wh;

        __syncthreads();             // stage(c+1) drained; cur free next iter
    }

    // per-wave partials -> bufA (wave w at f4 offset w*132)
    bufA[wave * 132 + lane]      = u0;
    bufA[wave * 132 + 64 + lane] = u1;
    if (lane < 4) bufA[wave * 132 + 128 + lane] = u2;
    __syncthreads();

    const float* red = (const float*)bufA;   // per-wave stride 528 floats
    float* outp = contribP + (size_t)blockIdx.x * S_;
    for (int s = tid; s < S_; s += 128) {
        float ul = red[s]       + red[528 + s];
        float uh = red[S_ + s]  + red[528 + S_ + s];
        float ph = x_phase[(size_t)b * S_ + s];
        outp[s] = cosf(ph) * ul + sinf(ph) * uh;
    }
}

// ---------------------------------------------------------------------------
// GEMM1 (fused cat): z = relu([q, v] @ W1^T + b1),
// q = x_mag + sum of 4 contrib partials (e0,e1,o0,o1 = rows b*4+{0..3}).
// Tile 32x64, thread 2x4, K-chunk 32.
// ---------------------------------------------------------------------------
__global__ __launch_bounds__(256) void k_gemm1(
    const float* __restrict__ x_mag, const float* __restrict__ contribP,
    const float* __restrict__ v, const float* __restrict__ W1,
    const float* __restrict__ b1, float* __restrict__ z)
{
    const int tid = threadIdx.x;
    const int m0  = blockIdx.x * 32;
    const int n0  = blockIdx.y * 64;
    const int trow = (tid >> 4) * 2;        // 0..30
    const int tcol = (tid & 15) * 4;        // 0..60

    __shared__ float As[32][36];   // As[k][r]
    __shared__ float Ws[32][68];   // Ws[k][c]

    float acc[2][4] = {};

    const int krA  = tid >> 3;        // 0..31
    const int kkA  = (tid & 7) * 4;   // 0..28

    for (int kc = 0; kc < NQ; kc += 32) {
        {
            const int arow = m0 + krA;
            const int gk = kc + kkA;
            float4 vv = {0.f, 0.f, 0.f, 0.f};
            if (gk < S_) {
                float4 xm = *(const float4*)&x_mag[(size_t)arow * S_ + gk];
                const float* cb = contribP + (size_t)(arow * 4) * S_ + gk;
                float4 c0 = *(const float4*)(cb);
                float4 c1 = *(const float4*)(cb + S_);
                float4 c2 = *(const float4*)(cb + 2 * S_);
                float4 c3 = *(const float4*)(cb + 3 * S_);
                vv.x = xm.x + c0.x + c1.x + c2.x + c3.x;
                vv.y = xm.y + c0.y + c1.y + c2.y + c3.y;
                vv.z = xm.z + c0.z + c1.z + c2.z + c3.z;
                vv.w = xm.w + c0.w + c1.w + c2.w + c3.w;
            } else if (gk < NQ) {
                vv = *(const float4*)&v[(size_t)arow * V_ + (gk - S_)];
            }
            As[kkA + 0][krA] = vv.x; As[kkA + 1][krA] = vv.y;
            As[kkA + 2][krA] = vv.z; As[kkA + 3][krA] = vv.w;
        }
        for (int i = tid; i < 512; i += 256) {
            const int r  = i >> 3;
            const int j4 = (i & 7) * 4;
            const int gk = kc + j4;
            float4 vv = {0.f, 0.f, 0.f, 0.f};
            if (gk < NQ)
                vv = *(const float4*)&W1[(size_t)(n0 + r) * NQ + gk];
            Ws[j4 + 0][r] = vv.x; Ws[j4 + 1][r] = vv.y;
            Ws[j4 + 2][r] = vv.z; Ws[j4 + 3][r] = vv.w;
        }
        __syncthreads();

        #pragma unroll
        for (int k = 0; k < 32; ++k) {
            float2 a2 = *(const float2*)&As[k][trow];
            float4 w4 = *(const float4*)&Ws[k][tcol];
            acc[0][0] += a2.x * w4.x; acc[0][1] += a2.x * w4.y;
            acc[0][2] += a2.x * w4.z; acc[0][3] += a2.x * w4.w;
            acc[1][0] += a2.y * w4.x; acc[1][1] += a2.y * w4.y;
            acc[1][2] += a2.y * w4.z; acc[1][3] += a2.y * w4.w;
        }
        __syncthreads();
    }

    #pragma unroll
    for (int i = 0; i < 2; ++i) {
        const int row = m0 + trow + i;
        const int col = n0 + tcol;
        float4 r;
        r.x = fmaxf(acc[i][0] + b1[col + 0], 0.f);
        r.y = fmaxf(acc[i][1] + b1[col + 1], 0.f);
        r.z = fmaxf(acc[i][2] + b1[col + 2], 0.f);
        r.w = fmaxf(acc[i][3] + b1[col + 3], 0.f);
        *(float4*)&z[(size_t)row * Z_ + col] = r;
    }
}

// ---------------------------------------------------------------------------
// GEMM23 (fused): [out_oh | out_v] = z @ [W2;W3]^T + [b2;b3] + [oh | v]
// plus fused softmax-MAPP epilogue writing out0's second half.
// ---------------------------------------------------------------------------
__global__ __launch_bounds__(256) void k_gemm23(
    const float* __restrict__ z,
    const float* __restrict__ W2, const float* __restrict__ b2,
    const float* __restrict__ oh,
    const float* __restrict__ W3, const float* __restrict__ b3,
    const float* __restrict__ v,
    float* __restrict__ out_oh, float* __restrict__ out_v,
    float* __restrict__ out0)
{
    const int tid = threadIdx.x;
    const int m0  = blockIdx.x * 32;
    const int n0  = blockIdx.y * 64;
    const int trow = (tid >> 4) * 2;
    const int tcol = (tid & 15) * 4;

    __shared__ float As[32][36];
    __shared__ float Ws[32][68];

    float acc[2][4] = {};

    const int krA = tid >> 3;
    const int kkA = (tid & 7) * 4;

    for (int kc = 0; kc < Z_; kc += 32) {
        {
            float4 vv = *(const float4*)&z[(size_t)(m0 + krA) * Z_ + kc + kkA];
            As[kkA + 0][krA] = vv.x; As[kkA + 1][krA] = vv.y;
            As[kkA + 2][krA] = vv.z; As[kkA + 3][krA] = vv.w;
        }
        for (int i = tid; i < 512; i += 256) {
            const int r  = i >> 3;
            const int j4 = (i & 7) * 4;
            const int wrow = n0 + r;
            float4 vv = {0.f, 0.f, 0.f, 0.f};
            if (wrow < NTOT) {
                const float* wp = (wrow < N2_)
                    ? (W2 + (size_t)wrow * Z_)
                    : (W3 + (size_t)(wrow - N2_) * Z_);
                vv = *(const float4*)&wp[kc + j4];
            }
            Ws[j4 + 0][r] = vv.x; Ws[j4 + 1][r] = vv.y;
            Ws[j4 + 2][r] = vv.z; Ws[j4 + 3][r] = vv.w;
        }
        __syncthreads();

        #pragma unroll
        for (int k = 0; k < 32; ++k) {
            float2 a2 = *(const float2*)&As[k][trow];
            float4 w4 = *(const float4*)&Ws[k][tcol];
            acc[0][0] += a2.x * w4.x; acc[0][1] += a2.x * w4.y;
            acc[0][2] += a2.x * w4.z; acc[0][3] += a2.x * w4.w;
            acc[1][0] += a2.y * w4.x; acc[1][1] += a2.y * w4.y;
            acc[1][2] += a2.y * w4.z; acc[1][3] += a2.y * w4.w;
        }
        __syncthreads();
    }

    #pragma unroll
    for (int i = 0; i < 2; ++i) {
        const int row = m0 + trow + i;
        const int col = n0 + tcol;
        if (col < N2_) {
            float4 ad = *(const float4*)&oh[(size_t)row * N2_ + col];
            float4 r;
            r.x = acc[i][0] + b2[col + 0] + ad.x;
            r.y = acc[i][1] + b2[col + 1] + ad.y;
            r.z = acc[i][2] + b2[col + 2] + ad.z;
            r.w = acc[i][3] + b2[col + 3] + ad.w;
            *(float4*)&out_oh[(size_t)row * N2_ + col] = r;
            float m  = fmaxf(fmaxf(r.x, r.y), fmaxf(r.z, r.w));
            float e0 = expf(r.x - m), e1 = expf(r.y - m);
            float e2 = expf(r.z - m), e3 = expf(r.w - m);
            float sum = e0 + e1 + e2 + e3;
            float sym = (0.5f * e0 + 1.0f * e1 + 1.5f * e2 + 2.0f * e3) / sum;
            out0[(size_t)B_ * S_ + (size_t)row * S_ + (col >> 2)] = sym;
        } else if (col < NTOT) {
            const int c3 = col - N2_;
            float4 ad = *(const float4*)&v[(size_t)row * V_ + c3];
            float4 r;
            r.x = acc[i][0] + b3[c3 + 0] + ad.x;
            r.y = acc[i][1] + b3[c3 + 1] + ad.y;
            r.z = acc[i][2] + b3[c3 + 2] + ad.z;
            r.w = acc[i][3] + b3[c3 + 3] + ad.w;
            *(float4*)&out_v[(size_t)row * V_ + c3] = r;
        }
    }
}

// ---------------------------------------------------------------------------
extern "C" void kernel_launch(void* const* d_in, const int* in_sizes, int n_in,
                              void* d_out, int out_size, void* d_ws, size_t ws_size,
                              hipStream_t stream)
{
    const float* x_mag    = (const float*)d_in[1];
    const float* x_mag_oh = (const float*)d_in[2];
    const float* v        = (const float*)d_in[3];
    const float* x_phase  = (const float*)d_in[4];
    const float* y_e      = (const float*)d_in[5];
    const float* y_o      = (const float*)d_in[6];
    const float* Psi_e    = (const float*)d_in[7];
    const float* Psi_o    = (const float*)d_in[8];
    const float* W1       = (const float*)d_in[9];
    const float* b1       = (const float*)d_in[10];
    const float* W2       = (const float*)d_in[11];
    const float* b2       = (const float*)d_in[12];
    const float* W3       = (const float*)d_in[13];
    const float* b3       = (const float*)d_in[14];
    const float* d1       = (const float*)d_in[15];
    const float* d2       = (const float*)d_in[16];
    const float* d4       = (const float*)d_in[18];   // d3 (d_in[17]) unused

    float* ws       = (float*)d_ws;
    float* contribP = ws;                        // 2048 * 264 (4 partials/batch)
    float* z        = contribP + 2048 * S_;      // 512 * 1024

    float* out0   = (float*)d_out;               // 2*512*264 (x_mag_new)
    float* out_oh = out0 + 2 * B_ * S_;          // 512*1056  (x_mag_oh_new)
    float* out_v  = out_oh + B_ * N2_;           // 512*128   (v_new)

    k_psi<<<dim3(B_ * 4), dim3(128), 0, stream>>>(
        x_mag, x_phase, y_e, y_o, Psi_e, Psi_o, d1, d2, d4, contribP, out0);

    k_gemm1<<<dim3(16, 16), dim3(256), 0, stream>>>(
        x_mag, contribP, v, W1, b1, z);

    k_gemm23<<<dim3(16, 19), dim3(256), 0, stream>>>(
        z, W2, b2, x_mag_oh, W3, b3, v, out_oh, out_v, out0);
}

// Round 8
// 275.081 us; speedup vs baseline: 1.1249x; 1.1050x over previous
//
#include <hip/hip_runtime.h>
#include <stdint.h>

#define S_     264
#define BL_    256
#define TWO_S  528
#define TWO_BL 512
#define B_     512
#define V_     128
#define NQ     392   // S + V
#define Z_     1024
#define N2_    1056  // S*4
#define NTOT   1184  // N2 + V

#define CH_F4  528   // per chunk: 2 pairs x (lo row 132 + hi row 132) float4

// async global->LDS, 16 bytes per lane (LDS dest = wave-uniform base + lane*16)
__device__ __forceinline__ void gload_lds16(const void* g, void* l) {
    __builtin_amdgcn_global_load_lds(
        (const __attribute__((address_space(1))) uint32_t*)g,
        (__attribute__((address_space(3))) uint32_t*)l, 16, 0, 0);
}

// stage chunk c: pairs (half*128 + c*2 + {0,1}), 528 float4, linear dest.
__device__ __forceinline__ void stage2(const float4* Pg, int half, int c,
                                       float4* buf, int tid) {
    #pragma unroll
    for (int r = 0; r < 4; ++r) {
        const int i  = r * 128 + tid;          // 0..511
        const int pi = (i >= 264) ? 1 : 0;
        const int o  = i - pi * 264;
        const int m  = half * 128 + c * 2 + pi;
        const float4* src = Pg + (size_t)((o < 132) ? (m * 132 + o)
                                                    : ((m + BL_) * 132 + (o - 132)));
        gload_lds16((const void*)src, (void*)(buf + i));
    }
    if (tid < 16) {
        const int i = 512 + tid;               // pi=1, o=248..263 -> hi row
        const int m = half * 128 + c * 2 + 1;
        const float4* src = Pg + (size_t)((m + BL_) * 132 + (i - 264 - 132));
        gload_lds16((const void*)src, (void*)(buf + i));
    }
}

// ---------------------------------------------------------------------------
// Kernel 1 (UNCHANGED from round-7 passing version): 2048 blocks x 128 thr;
// block = (batch, psi, half). LDS double-buffered gload_lds, 8 blocks/CU.
// ---------------------------------------------------------------------------
__global__ __launch_bounds__(128) void k_psi(
    const float* __restrict__ x_mag, const float* __restrict__ x_phase,
    const float* __restrict__ y_e, const float* __restrict__ y_o,
    const float* __restrict__ Psi_e, const float* __restrict__ Psi_o,
    const float* __restrict__ d1, const float* __restrict__ d2,
    const float* __restrict__ d4,
    float* __restrict__ contribP, float* __restrict__ out0)
{
    const int tid  = threadIdx.x;
    const int b    = blockIdx.x >> 2;
    const int psi  = (blockIdx.x >> 1) & 1;
    const int half = blockIdx.x & 1;
    const float* Psi = psi ? Psi_o : Psi_e;
    const float* yv  = psi ? y_o  : y_e;
    const float coefY = psi ? -d2[0] : -d1[0];
    const float coefS = psi ?  d4[0] :  d2[0];

    __shared__ float4 bufA[CH_F4];
    __shared__ float4 bufB[CH_F4];
    __shared__ float4 xs4[132];
    __shared__ float  gys[128];

    float* xs = (float*)xs4;

    for (int s = tid; s < S_; s += 128) {
        float mag = x_mag[(size_t)b * S_ + s];
        float ph  = x_phase[(size_t)b * S_ + s];
        xs[s]      = mag * cosf(ph);
        xs[S_ + s] = mag * sinf(ph);
        if (psi == 0 && half == 0) out0[(size_t)b * S_ + s] = mag;
    }
    gys[tid] = coefY * yv[(size_t)b * BL_ + half * 128 + tid];

    const float4* Pg = (const float4*)(Psi + (size_t)b * TWO_BL * TWO_S);

    stage2(Pg, half, 0, bufA, tid);
    __syncthreads();

    const int wave = tid >> 6, lane = tid & 63;
    const float4 f4z = {0.f, 0.f, 0.f, 0.f};

    float4 x0 = xs4[lane];
    float4 x1 = xs4[lane + 64];
    float4 x2 = (lane < 4) ? xs4[lane + 128] : f4z;

    float4 u0 = f4z, u1 = f4z, u2 = f4z;

    for (int c = 0; c < 64; ++c) {
        float4* cur = (c & 1) ? bufB : bufA;
        float4* nxt = (c & 1) ? bufA : bufB;
        if (c + 1 < 64) stage2(Pg, half, c + 1, nxt, tid);

        const float4* bl = cur + wave * 264;
        const float4* bh = bl + 132;
        float4 l0 = bl[lane], l1 = bl[lane + 64];
        float4 h0 = bh[lane], h1 = bh[lane + 64];
        float4 l2 = f4z, h2 = f4z;
        if (lane < 4) { l2 = bl[lane + 128]; h2 = bh[lane + 128]; }

        float a  = l0.x*x0.x + l0.y*x0.y + l0.z*x0.z + l0.w*x0.w
                 + l1.x*x1.x + l1.y*x1.y + l1.z*x1.z + l1.w*x1.w
                 + l2.x*x2.x + l2.y*x2.y + l2.z*x2.z + l2.w*x2.w;
        float bb = h0.x*x0.x + h0.y*x0.y + h0.z*x0.z + h0.w*x0.w
                 + h1.x*x1.x + h1.y*x1.y + h1.z*x1.z + h1.w*x1.w
                 + h2.x*x2.x + h2.y*x2.y + h2.z*x2.z + h2.w*x2.w;
        #pragma unroll
        for (int off = 32; off; off >>= 1) {
            a  += __shfl_xor(a, off);
            bb += __shfl_xor(bb, off);
        }

        const float g  = gys[c * 2 + wave] + coefS * (a * a + bb * bb);
        const float wl = a * g, wh = bb * g;

        u0.x += l0.x*wl + h0.x*wh;  u0.y += l0.y*wl + h0.y*wh;
        u0.z += l0.z*wl + h0.z*wh;  u0.w += l0.w*wl + h0.w*wh;
        u1.x += l1.x*wl + h1.x*wh;  u1.y += l1.y*wl + h1.y*wh;
        u1.z += l1.z*wl + h1.z*wh;  u1.w += l1.w*wl + h1.w*wh;
        u2.x += l2.x*wl + h2.x*wh;  u2.y += l2.y*wl + h2.y*wh;
        u2.z += l2.z*wl + h2.z*wh;  u2.w += l2.w*wl + h2.w*wh;

        __syncthreads();
    }

    bufA[wave * 132 + lane]      = u0;
    bufA[wave * 132 + 64 + lane] = u1;
    if (lane < 4) bufA[wave * 132 + 128 + lane] = u2;
    __syncthreads();

    const float* red = (const float*)bufA;
    float* outp = contribP + (size_t)blockIdx.x * S_;
    for (int s = tid; s < S_; s += 128) {
        float ul = red[s]       + red[528 + s];
        float uh = red[S_ + s]  + red[528 + S_ + s];
        float ph = x_phase[(size_t)b * S_ + s];
        outp[s] = cosf(ph) * ul + sinf(ph) * uh;
    }
}

// ---------------------------------------------------------------------------
// GEMM1 (fused cat): z = relu([q, v] @ W1^T + b1),
// q = x_mag + sum of 4 contrib partials. Tile 32x32, thread 1x4, BK=32.
// Grid (16, 32) = 512 blocks -> 2 blocks/CU.
// ---------------------------------------------------------------------------
__global__ __launch_bounds__(256) void k_gemm1(
    const float* __restrict__ x_mag, const float* __restrict__ contribP,
    const float* __restrict__ v, const float* __restrict__ W1,
    const float* __restrict__ b1, float* __restrict__ z)
{
    const int tid  = threadIdx.x;
    const int m0   = blockIdx.x * 32;
    const int n0   = blockIdx.y * 32;
    const int trow = tid >> 3;          // 0..31 (1 row)
    const int tcol = (tid & 7) * 4;     // 0..28 (4 cols)

    __shared__ float As[32][33];   // As[k][r]
    __shared__ float Ws[32][36];   // Ws[k][c], 16B-aligned rows

    float4 acc = {0.f, 0.f, 0.f, 0.f};

    const int krA = tid >> 3;        // 0..31 (row index for staging)
    const int kkA = (tid & 7) * 4;   // 0..28 (k offset for staging)

    for (int kc = 0; kc < NQ; kc += 32) {
        // ---- stage A (cat built on the fly): 1 float4 per thread
        {
            const int arow = m0 + krA;
            const int gk = kc + kkA;
            float4 vv = {0.f, 0.f, 0.f, 0.f};
            if (gk < S_) {
                float4 xm = *(const float4*)&x_mag[(size_t)arow * S_ + gk];
                const float* cb = contribP + (size_t)(arow * 4) * S_ + gk;
                float4 c0 = *(const float4*)(cb);
                float4 c1 = *(const float4*)(cb + S_);
                float4 c2 = *(const float4*)(cb + 2 * S_);
                float4 c3 = *(const float4*)(cb + 3 * S_);
                vv.x = xm.x + c0.x + c1.x + c2.x + c3.x;
                vv.y = xm.y + c0.y + c1.y + c2.y + c3.y;
                vv.z = xm.z + c0.z + c1.z + c2.z + c3.z;
                vv.w = xm.w + c0.w + c1.w + c2.w + c3.w;
            } else if (gk < NQ) {
                vv = *(const float4*)&v[(size_t)arow * V_ + (gk - S_)];
            }
            As[kkA + 0][krA] = vv.x; As[kkA + 1][krA] = vv.y;
            As[kkA + 2][krA] = vv.z; As[kkA + 3][krA] = vv.w;
        }
        // ---- stage W: 1 float4 per thread
        {
            const int wrow = n0 + krA;
            const int gk = kc + kkA;
            float4 vv = {0.f, 0.f, 0.f, 0.f};
            if (gk < NQ)
                vv = *(const float4*)&W1[(size_t)wrow * NQ + gk];
            Ws[kkA + 0][krA] = vv.x; Ws[kkA + 1][krA] = vv.y;
            Ws[kkA + 2][krA] = vv.z; Ws[kkA + 3][krA] = vv.w;
        }
        __syncthreads();

        #pragma unroll
        for (int k = 0; k < 32; ++k) {
            float  a  = As[k][trow];
            float4 w4 = *(const float4*)&Ws[k][tcol];
            acc.x += a * w4.x; acc.y += a * w4.y;
            acc.z += a * w4.z; acc.w += a * w4.w;
        }
        __syncthreads();
    }

    const int row = m0 + trow;
    const int col = n0 + tcol;
    float4 r;
    r.x = fmaxf(acc.x + b1[col + 0], 0.f);
    r.y = fmaxf(acc.y + b1[col + 1], 0.f);
    r.z = fmaxf(acc.z + b1[col + 2], 0.f);
    r.w = fmaxf(acc.w + b1[col + 3], 0.f);
    *(float4*)&z[(size_t)row * Z_ + col] = r;
}

// ---------------------------------------------------------------------------
// GEMM23 (fused): [out_oh | out_v] = z @ [W2;W3]^T + [b2;b3] + [oh | v]
// plus fused softmax-MAPP epilogue. Tile 32x32, thread 1x4, BK=32.
// Grid (16, 37) = 592 blocks -> ~2.3 blocks/CU.
// ---------------------------------------------------------------------------
__global__ __launch_bounds__(256) void k_gemm23(
    const float* __restrict__ z,
    const float* __restrict__ W2, const float* __restrict__ b2,
    const float* __restrict__ oh,
    const float* __restrict__ W3, const float* __restrict__ b3,
    const float* __restrict__ v,
    float* __restrict__ out_oh, float* __restrict__ out_v,
    float* __restrict__ out0)
{
    const int tid  = threadIdx.x;
    const int m0   = blockIdx.x * 32;
    const int n0   = blockIdx.y * 32;
    const int trow = tid >> 3;
    const int tcol = (tid & 7) * 4;

    __shared__ float As[32][33];
    __shared__ float Ws[32][36];

    float4 acc = {0.f, 0.f, 0.f, 0.f};

    const int krA = tid >> 3;
    const int kkA = (tid & 7) * 4;

    for (int kc = 0; kc < Z_; kc += 32) {
        {
            float4 vv = *(const float4*)&z[(size_t)(m0 + krA) * Z_ + kc + kkA];
            As[kkA + 0][krA] = vv.x; As[kkA + 1][krA] = vv.y;
            As[kkA + 2][krA] = vv.z; As[kkA + 3][krA] = vv.w;
        }
        {
            const int wrow = n0 + krA;
            float4 vv;
            const float* wp = (wrow < N2_)
                ? (W2 + (size_t)wrow * Z_)
                : (W3 + (size_t)(wrow - N2_) * Z_);
            vv = *(const float4*)&wp[kc + kkA];
            Ws[kkA + 0][krA] = vv.x; Ws[kkA + 1][krA] = vv.y;
            Ws[kkA + 2][krA] = vv.z; Ws[kkA + 3][krA] = vv.w;
        }
        __syncthreads();

        #pragma unroll
        for (int k = 0; k < 32; ++k) {
            float  a  = As[k][trow];
            float4 w4 = *(const float4*)&Ws[k][tcol];
            acc.x += a * w4.x; acc.y += a * w4.y;
            acc.z += a * w4.z; acc.w += a * w4.w;
        }
        __syncthreads();
    }

    const int row = m0 + trow;
    const int col = n0 + tcol;
    if (col < N2_) {
        float4 ad = *(const float4*)&oh[(size_t)row * N2_ + col];
        float4 r;
        r.x = acc.x + b2[col + 0] + ad.x;
        r.y = acc.y + b2[col + 1] + ad.y;
        r.z = acc.z + b2[col + 2] + ad.z;
        r.w = acc.w + b2[col + 3] + ad.w;
        *(float4*)&out_oh[(size_t)row * N2_ + col] = r;
        float m  = fmaxf(fmaxf(r.x, r.y), fmaxf(r.z, r.w));
        float e0 = expf(r.x - m), e1 = expf(r.y - m);
        float e2 = expf(r.z - m), e3 = expf(r.w - m);
        float sum = e0 + e1 + e2 + e3;
        float sym = (0.5f * e0 + 1.0f * e1 + 1.5f * e2 + 2.0f * e3) / sum;
        out0[(size_t)B_ * S_ + (size_t)row * S_ + (col >> 2)] = sym;
    } else {
        const int c3 = col - N2_;
        float4 ad = *(const float4*)&v[(size_t)row * V_ + c3];
        float4 r;
        r.x = acc.x + b3[c3 + 0] + ad.x;
        r.y = acc.y + b3[c3 + 1] + ad.y;
        r.z = acc.z + b3[c3 + 2] + ad.z;
        r.w = acc.w + b3[c3 + 3] + ad.w;
        *(float4*)&out_v[(size_t)row * V_ + c3] = r;
    }
}

// ---------------------------------------------------------------------------
extern "C" void kernel_launch(void* const* d_in, const int* in_sizes, int n_in,
                              void* d_out, int out_size, void* d_ws, size_t ws_size,
                              hipStream_t stream)
{
    const float* x_mag    = (const float*)d_in[1];
    const float* x_mag_oh = (const float*)d_in[2];
    const float* v        = (const float*)d_in[3];
    const float* x_phase  = (const float*)d_in[4];
    const float* y_e      = (const float*)d_in[5];
    const float* y_o      = (const float*)d_in[6];
    const float* Psi_e    = (const float*)d_in[7];
    const float* Psi_o    = (const float*)d_in[8];
    const float* W1       = (const float*)d_in[9];
    const float* b1       = (const float*)d_in[10];
    const float* W2       = (const float*)d_in[11];
    const float* b2       = (const float*)d_in[12];
    const float* W3       = (const float*)d_in[13];
    const float* b3       = (const float*)d_in[14];
    const float* d1       = (const float*)d_in[15];
    const float* d2       = (const float*)d_in[16];
    const float* d4       = (const float*)d_in[18];   // d3 (d_in[17]) unused

    float* ws       = (float*)d_ws;
    float* contribP = ws;                        // 2048 * 264 (4 partials/batch)
    float* z        = contribP + 2048 * S_;      // 512 * 1024

    float* out0   = (float*)d_out;               // 2*512*264 (x_mag_new)
    float* out_oh = out0 + 2 * B_ * S_;          // 512*1056  (x_mag_oh_new)
    float* out_v  = out_oh + B_ * N2_;           // 512*128   (v_new)

    k_psi<<<dim3(B_ * 4), dim3(128), 0, stream>>>(
        x_mag, x_phase, y_e, y_o, Psi_e, Psi_o, d1, d2, d4, contribP, out0);

    k_gemm1<<<dim3(16, 32), dim3(256), 0, stream>>>(
        x_mag, contribP, v, W1, b1, z);

    k_gemm23<<<dim3(16, 37), dim3(256), 0, stream>>>(
        z, W2, b2, x_mag_oh, W3, b3, v, out_oh, out_v, out0);
}